// Round 9
// baseline (213.060 us; speedup 1.0000x reference)
//
#include <hip/hip_runtime.h>

typedef __attribute__((ext_vector_type(8))) short short8;
typedef __attribute__((ext_vector_type(4))) float f32x4;

__device__ __forceinline__ unsigned short f2b(float x) {
  unsigned u = __float_as_uint(x);
  u += 0x7FFF + ((u >> 16) & 1);           // round-to-nearest-even
  return (unsigned short)(u >> 16);
}
__device__ __forceinline__ float b2f_lo(unsigned v) { return __uint_as_float(v << 16); }
__device__ __forceinline__ float b2f_hi(unsigned v) { return __uint_as_float(v & 0xFFFF0000u); }

#define EPB 4096   // edges per partition block
#define BKT 256    // nodes per bucket
#define RPW 32     // rows per wave in pooling

// fused setup: blocks [0,16) prepW W1, [16,32) prepW W2, [32, 32+neb) histogram
__global__ __launch_bounds__(256) void k_setup(
    const float* __restrict__ W1, unsigned short* __restrict__ Wt1,
    const float* __restrict__ W2, unsigned short* __restrict__ Wt2,
    const int* __restrict__ dst, int E, int nbuck, int* __restrict__ mat)
{
  __shared__ float tile[32][33];
  __shared__ int h[256];
  int t = threadIdx.x;
  if (blockIdx.x < 32) {
    const float* W = (blockIdx.x < 16) ? W1 : W2;
    unsigned short* Wt = (blockIdx.x < 16) ? Wt1 : Wt2;
    int bid = blockIdx.x & 15;
    int tx = t & 31, ty = t >> 5;
    int bx = bid & 3, by = bid >> 2;
    #pragma unroll
    for (int i = 0; i < 4; ++i)
      tile[ty + i * 8][tx] = W[(by * 32 + ty + i * 8) * 128 + bx * 32 + tx];
    __syncthreads();
    #pragma unroll
    for (int i = 0; i < 4; ++i)
      Wt[(bx * 32 + ty + i * 8) * 128 + by * 32 + tx] = f2b(tile[tx][ty + i * 8]);
  } else {
    int blk = blockIdx.x - 32;
    h[t] = 0;
    __syncthreads();
    int e0 = blk * EPB, e1 = min(e0 + EPB, E);
    for (int e = e0 + t; e < e1; e += 256) atomicAdd(&h[dst[e] >> 8], 1);
    __syncthreads();
    if (t < nbuck) mat[blk * nbuck + t] = h[t];
  }
}

// one block per bucket: READ-ONLY recompute of bucket totals from mat (coalesced
// column-sums), scan -> boff; column-scan own column -> bases into matB (separate
// buffer: no block writes what another reads). Also zeroes sums/cnt.
__global__ __launch_bounds__(256) void k_offsets(
    const int* __restrict__ mat, int* __restrict__ matB, int neb, int nbuck,
    int* __restrict__ boff, int* __restrict__ rowptr, int N_,
    float* __restrict__ sums, int* __restrict__ cnt, int ng)
{
  __shared__ int s[256];
  int b = blockIdx.x, t = threadIdx.x;
  // column totals (thread t owns column t)
  int tsum = 0;
  if (t < nbuck)
    for (int r = 0; r < neb; ++r) tsum += mat[r * nbuck + t];
  s[t] = tsum;
  __syncthreads();
  #pragma unroll
  for (int d = 1; d < 256; d <<= 1) {
    int u = (t >= d) ? s[t - d] : 0;
    __syncthreads();
    s[t] += u;
    __syncthreads();
  }
  int excl = s[t] - tsum;                 // exclusive bucket offset for bucket t
  if (t == b && t < nbuck) boff[b] = excl;
  if (b == 0 && t == 0) { boff[nbuck] = s[255]; rowptr[N_] = s[255]; }
  __syncthreads();
  s[t] = excl;
  __syncthreads();
  int base = s[b];
  __syncthreads();
  // exclusive scan down column b of mat -> matB
  int v = (t < neb) ? mat[t * nbuck + b] : 0;
  s[t] = v;
  __syncthreads();
  #pragma unroll
  for (int d = 1; d < 256; d <<= 1) {
    int u = (t >= d) ? s[t - d] : 0;
    __syncthreads();
    s[t] += u;
    __syncthreads();
  }
  if (t < neb) matB[t * nbuck + b] = base + s[t] - v;
  // zero pooling buffers
  int tot_e = ng * 128;
  for (int i = b * 256 + t; i < tot_e; i += gridDim.x * 256) sums[i] = 0.f;
  for (int i = b * 256 + t; i < ng; i += gridDim.x * 256) cnt[i] = 0;
}

// scatter edges into bucket-grouped staging: staged = (dst&255)<<16 | src  (uint16 each)
__global__ __launch_bounds__(256) void k_part(const int* __restrict__ src,
                                              const int* __restrict__ dst, int E, int nbuck,
                                              const int* __restrict__ matB,
                                              unsigned* __restrict__ staged) {
  __shared__ int cur[256];
  int t = threadIdx.x;
  if (t < nbuck) cur[t] = matB[blockIdx.x * nbuck + t];
  __syncthreads();
  int e0 = blockIdx.x * EPB, e1 = min(e0 + EPB, E);
  for (int e = e0 + t; e < e1; e += 256) {
    int d = dst[e];
    int pos = atomicAdd(&cur[d >> 8], 1);
    staged[pos] = ((unsigned)(d & 255) << 16) | (unsigned)src[e];
  }
}

// one block per bucket: per-node count (LDS) -> rowptr + dinv, then place csr entries (uint16)
__global__ __launch_bounds__(256) void k_csr(const unsigned* __restrict__ staged,
                                             const int* __restrict__ boff, int N_,
                                             float* __restrict__ dinv, int* __restrict__ rowptr,
                                             unsigned short* __restrict__ csr16) {
  __shared__ int cnt[256];
  __shared__ int cur[256];
  int b = blockIdx.x, t = threadIdx.x;
  int lo = boff[b], hi = boff[b + 1];
  cnt[t] = 0;
  __syncthreads();
  for (int i = lo + t; i < hi; i += 256) atomicAdd(&cnt[staged[i] >> 16], 1);
  __syncthreads();
  int v = cnt[t];
  #pragma unroll
  for (int d = 1; d < 256; d <<= 1) {
    int u = (t >= d) ? cnt[t - d] : 0;
    __syncthreads();
    cnt[t] += u;
    __syncthreads();
  }
  int start = lo + cnt[t] - v;     // exclusive within bucket
  cur[t] = start;
  int node = (b << 8) + t;
  if (node < N_) {
    rowptr[node] = start;
    dinv[node] = rsqrtf((float)(v + 1));
  }
  __syncthreads();
  for (int i = lo + t; i < hi; i += 256) {
    unsigned e = staged[i];
    int pos = atomicAdd(&cur[e >> 16], 1);
    csr16[pos] = (unsigned short)(e & 0xFFFFu);
  }
}

// Out[r][c] = bf16( (sum_k A[r][k]*W[k][c]) * dinv[r] ).  A: f32 (A_F32=1) or bf16.
template<int A_F32>
__global__ __launch_bounds__(256) void k_mfma_gemm(
    const void* __restrict__ Ap, const unsigned short* __restrict__ Wt,
    const float* __restrict__ dinv, unsigned short* __restrict__ Out, int M)
{
  int wv = threadIdx.x >> 6, lane = threadIdx.x & 63;
  int r0 = blockIdx.x * 64 + wv * 16;
  if (r0 >= M) return;
  int arow = r0 + (lane & 15);
  int kb = (lane >> 4) * 8;
  short8 a[4];
  if (A_F32) {
    const float* Ar = (const float*)Ap + (size_t)arow * 128 + kb;
    #pragma unroll
    for (int ks = 0; ks < 4; ++ks) {
      float4 u = *(const float4*)(Ar + ks * 32);
      float4 v = *(const float4*)(Ar + ks * 32 + 4);
      short8 tt;
      tt[0] = (short)f2b(u.x); tt[1] = (short)f2b(u.y);
      tt[2] = (short)f2b(u.z); tt[3] = (short)f2b(u.w);
      tt[4] = (short)f2b(v.x); tt[5] = (short)f2b(v.y);
      tt[6] = (short)f2b(v.z); tt[7] = (short)f2b(v.w);
      a[ks] = tt;
    }
  } else {
    const unsigned short* Ar = (const unsigned short*)Ap + (size_t)arow * 128 + kb;
    #pragma unroll
    for (int ks = 0; ks < 4; ++ks)
      a[ks] = *(const short8*)(Ar + ks * 32);
  }
  f32x4 acc[8];
  #pragma unroll
  for (int i = 0; i < 8; ++i) acc[i] = (f32x4){0.f, 0.f, 0.f, 0.f};
  const unsigned short* Bc = Wt + (size_t)(lane & 15) * 128 + kb;
  #pragma unroll
  for (int ct = 0; ct < 8; ++ct) {
    const unsigned short* B = Bc + ct * 16 * 128;
    #pragma unroll
    for (int ks = 0; ks < 4; ++ks)
      acc[ct] = __builtin_amdgcn_mfma_f32_16x16x32_bf16(
          a[ks], *(const short8*)(B + ks * 32), acc[ct], 0, 0, 0);
  }
  int orow = r0 + (lane >> 4) * 4;
  int ocol = lane & 15;
  float s0 = dinv[orow], s1 = dinv[orow + 1], s2 = dinv[orow + 2], s3 = dinv[orow + 3];
  #pragma unroll
  for (int ct = 0; ct < 8; ++ct) {
    unsigned short* o = Out + (size_t)orow * 128 + ct * 16 + ocol;
    o[0]   = f2b(acc[ct][0] * s0);
    o[128] = f2b(acc[ct][1] * s1);
    o[256] = f2b(acc[ct][2] * s2);
    o[384] = f2b(acc[ct][3] * s3);
  }
}

// half-wave (32 lanes) per dst node, uint2 (4 cols) per lane, 4-wide unrolled edge loop
__global__ __launch_bounds__(256) void k_gather_post(
    const unsigned short* __restrict__ csr16, const int* __restrict__ rowptr,
    const unsigned short* __restrict__ P, const float* __restrict__ dinv,
    const float* __restrict__ bias, unsigned short* __restrict__ R, int n)
{
  int node = blockIdx.x * 8 + (threadIdx.x >> 5);
  if (node >= n) return;
  int lane = threadIdx.x & 31;
  int lo = rowptr[node], hi = rowptr[node + 1];
  float a0 = 0.f, a1 = 0.f, a2 = 0.f, a3 = 0.f;
  int e = lo;
  for (; e + 4 <= hi; e += 4) {
    int s0 = csr16[e], s1 = csr16[e + 1], s2 = csr16[e + 2], s3 = csr16[e + 3];
    uint2 v0 = ((const uint2*)(P + (size_t)s0 * 128))[lane];
    uint2 v1 = ((const uint2*)(P + (size_t)s1 * 128))[lane];
    uint2 v2 = ((const uint2*)(P + (size_t)s2 * 128))[lane];
    uint2 v3 = ((const uint2*)(P + (size_t)s3 * 128))[lane];
    a0 += b2f_lo(v0.x) + b2f_lo(v1.x) + b2f_lo(v2.x) + b2f_lo(v3.x);
    a1 += b2f_hi(v0.x) + b2f_hi(v1.x) + b2f_hi(v2.x) + b2f_hi(v3.x);
    a2 += b2f_lo(v0.y) + b2f_lo(v1.y) + b2f_lo(v2.y) + b2f_lo(v3.y);
    a3 += b2f_hi(v0.y) + b2f_hi(v1.y) + b2f_hi(v2.y) + b2f_hi(v3.y);
  }
  for (; e < hi; ++e) {
    int s = csr16[e];
    uint2 v = ((const uint2*)(P + (size_t)s * 128))[lane];
    a0 += b2f_lo(v.x); a1 += b2f_hi(v.x);
    a2 += b2f_lo(v.y); a3 += b2f_hi(v.y);
  }
  float dv = dinv[node];
  uint2 hv = ((const uint2*)(P + (size_t)node * 128))[lane];
  float4 bb = ((const float4*)bias)[lane];
  float r0 = fmaxf(dv * (a0 + b2f_lo(hv.x)) + bb.x, 0.f);
  float r1 = fmaxf(dv * (a1 + b2f_hi(hv.x)) + bb.y, 0.f);
  float r2 = fmaxf(dv * (a2 + b2f_lo(hv.y)) + bb.z, 0.f);
  float r3 = fmaxf(dv * (a3 + b2f_hi(hv.y)) + bb.w, 0.f);
  uint2 pack;
  pack.x = (unsigned)f2b(r0) | ((unsigned)f2b(r1) << 16);
  pack.y = (unsigned)f2b(r2) | ((unsigned)f2b(r3) << 16);
  ((uint2*)(R + (size_t)node * 128))[lane] = pack;
}

// segmented mean-pool partial sums (batch sorted): wave owns RPW contiguous rows
__global__ __launch_bounds__(256) void k_pool_sum(
    const unsigned short* __restrict__ h2, const int* __restrict__ batch, int n,
    float* __restrict__ sums, int* __restrict__ cnt)
{
  int wid = blockIdx.x * 4 + (threadIdx.x >> 6);
  int lane = threadIdx.x & 63;
  int r0 = wid * RPW;
  if (r0 >= n) return;
  int r1 = min(r0 + RPW, n);
  const unsigned* H = (const unsigned*)h2;
  int gcur = batch[r0];
  float ax = 0.f, ay = 0.f;
  int run = 0;
  for (int r = r0; r < r1; ++r) {
    int g = batch[r];
    if (g != gcur) {
      atomicAdd(&sums[(size_t)gcur * 128 + 2 * lane], ax);
      atomicAdd(&sums[(size_t)gcur * 128 + 2 * lane + 1], ay);
      if (lane == 0) atomicAdd(&cnt[gcur], run);
      ax = ay = 0.f; run = 0; gcur = g;
    }
    unsigned v = H[(size_t)r * 64 + lane];
    ax += b2f_lo(v); ay += b2f_hi(v); ++run;
  }
  atomicAdd(&sums[(size_t)gcur * 128 + 2 * lane], ax);
  atomicAdd(&sums[(size_t)gcur * 128 + 2 * lane + 1], ay);
  if (lane == 0) atomicAdd(&cnt[gcur], run);
}

// per-graph MLP head: 4-chain ILP FC1, LDS-tree FC2
__global__ __launch_bounds__(128) void k_fc(
    const float* __restrict__ sums, const int* __restrict__ cnt,
    const float* __restrict__ Wf1, const float* __restrict__ bf1,
    const float* __restrict__ Wf2, const float* __restrict__ bf2,
    float* __restrict__ out)
{
  __shared__ float gl[128];
  __shared__ float red0[128];
  __shared__ float red1[128];
  int g = blockIdx.x, t = threadIdx.x;
  float c = (float)cnt[g];
  gl[t] = sums[(size_t)g * 128 + t] / fmaxf(c, 1.f);
  __syncthreads();
  float z0 = 0.f, z1 = 0.f, z2 = 0.f, z3 = 0.f;
  #pragma unroll
  for (int k = 0; k < 32; ++k) {
    z0 += gl[k]      * Wf1[k * 128 + t];
    z1 += gl[k + 32] * Wf1[(k + 32) * 128 + t];
    z2 += gl[k + 64] * Wf1[(k + 64) * 128 + t];
    z3 += gl[k + 96] * Wf1[(k + 96) * 128 + t];
  }
  float z = fmaxf((z0 + z1) + (z2 + z3) + bf1[t], 0.f);
  red0[t] = z * Wf2[2 * t];
  red1[t] = z * Wf2[2 * t + 1];
  __syncthreads();
  #pragma unroll
  for (int d = 64; d > 0; d >>= 1) {
    if (t < d) { red0[t] += red0[t + d]; red1[t] += red1[t + d]; }
    __syncthreads();
  }
  if (t == 0) {
    out[g * 2]     = red0[0] + bf2[0];
    out[g * 2 + 1] = red1[0] + bf2[1];
  }
}

extern "C" void kernel_launch(void* const* d_in, const int* in_sizes, int n_in,
                              void* d_out, int out_size, void* d_ws, size_t ws_size,
                              hipStream_t stream) {
  const float* x    = (const float*)d_in[0];
  const int*   ei   = (const int*)d_in[1];
  const int*   batch= (const int*)d_in[2];
  const float* W1   = (const float*)d_in[3];
  const float* b1   = (const float*)d_in[4];
  const float* W2   = (const float*)d_in[5];
  const float* b2   = (const float*)d_in[6];
  const float* Wf1  = (const float*)d_in[7];
  const float* bf1  = (const float*)d_in[8];
  const float* Wf2  = (const float*)d_in[9];
  const float* bf2  = (const float*)d_in[10];
  float* out = (float*)d_out;

  const int N  = in_sizes[0] / 128;    // requires N < 65536 for uint16 csr entries
  const int E  = in_sizes[1] / 2;
  const int NG = out_size / 2;
  const int* srcp = ei;
  const int* dstp = ei + E;

  const int nbuck = (N + BKT - 1) / BKT;     // <= 256
  const int neb   = (E + EPB - 1) / EPB;     // <= 256

  char* ws = (char*)d_ws;
  size_t off = 0;
  auto carve = [&](size_t bytes) { void* p = ws + off; off += (bytes + 255) & ~(size_t)255; return p; };
  float* dinv   = (float*)carve((size_t)N * 4);
  int*   rowptr = (int*)  carve((size_t)(N + 1) * 4);
  int*   boff   = (int*)  carve((size_t)(nbuck + 1) * 4);
  int*   mat    = (int*)  carve((size_t)neb * nbuck * 4);
  int*   matB   = (int*)  carve((size_t)neb * nbuck * 4);
  unsigned*       staged = (unsigned*)      carve((size_t)E * 4);
  unsigned short* csr16  = (unsigned short*)carve((size_t)E * 2);
  unsigned short* Wt1 = (unsigned short*)carve(128 * 128 * 2);
  unsigned short* Wt2 = (unsigned short*)carve(128 * 128 * 2);
  float* sums   = (float*)carve((size_t)NG * 128 * 4);
  int*   cntg   = (int*)  carve((size_t)NG * 4);
  const size_t nb_row = (size_t)N * 128 * 2;   // bf16 rows
  unsigned short* U0 = (unsigned short*)carve(nb_row);
  unsigned short* U1 = (unsigned short*)carve(nb_row);

  // fused weight-prep + histogram
  k_setup<<<32 + neb, 256, 0, stream>>>(W1, Wt1, W2, Wt2, dstp, E, nbuck, mat);
  // bucket offsets + per-(blk,bucket) bases (read mat, write matB) + zero pooling bufs
  k_offsets<<<nbuck, 256, 0, stream>>>(mat, matB, neb, nbuck, boff, rowptr, N, sums, cntg, NG);
  k_part<<<neb, 256, 0, stream>>>(srcp, dstp, E, nbuck, matB, staged);
  k_csr <<<nbuck, 256, 0, stream>>>(staged, boff, N, dinv, rowptr, csr16);

  const int gblocks = (N + 63) / 64;
  // layer 1
  k_mfma_gemm<1><<<gblocks, 256, 0, stream>>>(x, Wt1, dinv, U0, N);
  k_gather_post<<<(N + 7) / 8, 256, 0, stream>>>(csr16, rowptr, U0, dinv, b1, U1, N);
  // layer 2
  k_mfma_gemm<0><<<gblocks, 256, 0, stream>>>(U1, Wt2, dinv, U0, N);
  k_gather_post<<<(N + 7) / 8, 256, 0, stream>>>(csr16, rowptr, U0, dinv, b2, U1, N);

  // pooling + MLP head
  const int pblocks = (N + RPW * 4 - 1) / (RPW * 4);
  k_pool_sum<<<pblocks, 256, 0, stream>>>(U1, batch, N, sums, cntg);
  k_fc<<<NG, 128, 0, stream>>>(sums, cntg, Wf1, bf1, Wf2, bf2, out);
}

// Round 10
// 177.340 us; speedup vs baseline: 1.2014x; 1.2014x over previous
//
#include <hip/hip_runtime.h>

typedef __attribute__((ext_vector_type(8))) short short8;
typedef __attribute__((ext_vector_type(4))) float f32x4;

__device__ __forceinline__ unsigned short f2b(float x) {
  unsigned u = __float_as_uint(x);
  u += 0x7FFF + ((u >> 16) & 1);           // round-to-nearest-even
  return (unsigned short)(u >> 16);
}
__device__ __forceinline__ float b2f_lo(unsigned v) { return __uint_as_float(v << 16); }
__device__ __forceinline__ float b2f_hi(unsigned v) { return __uint_as_float(v & 0xFFFF0000u); }

#define EPB 4096   // edges per partition block
#define BKT 256    // nodes per bucket
#define RPW 32     // rows per wave in pooling

// fused setup: blocks [0,16) prepW W1, [16,32) prepW W2, [32, 32+neb) histogram
__global__ __launch_bounds__(256) void k_setup(
    const float* __restrict__ W1, unsigned short* __restrict__ Wt1,
    const float* __restrict__ W2, unsigned short* __restrict__ Wt2,
    const int* __restrict__ dst, int E, int nbuck, int* __restrict__ mat)
{
  __shared__ float tile[32][33];
  __shared__ int h[256];
  int t = threadIdx.x;
  if (blockIdx.x < 32) {
    const float* W = (blockIdx.x < 16) ? W1 : W2;
    unsigned short* Wt = (blockIdx.x < 16) ? Wt1 : Wt2;
    int bid = blockIdx.x & 15;
    int tx = t & 31, ty = t >> 5;
    int bx = bid & 3, by = bid >> 2;
    #pragma unroll
    for (int i = 0; i < 4; ++i)
      tile[ty + i * 8][tx] = W[(by * 32 + ty + i * 8) * 128 + bx * 32 + tx];
    __syncthreads();
    #pragma unroll
    for (int i = 0; i < 4; ++i)
      Wt[(bx * 32 + ty + i * 8) * 128 + by * 32 + tx] = f2b(tile[tx][ty + i * 8]);
  } else {
    int blk = blockIdx.x - 32;
    h[t] = 0;
    __syncthreads();
    int e0 = blk * EPB, e1 = min(e0 + EPB, E);
    for (int e = e0 + t; e < e1; e += 256) atomicAdd(&h[dst[e] >> 8], 1);
    __syncthreads();
    if (t < nbuck) mat[blk * nbuck + t] = h[t];
  }
}

// ONE block: bucket totals = column sums of mat (coalesced, unrolled), scan -> boff
__global__ __launch_bounds__(256) void k_excl(const int* __restrict__ mat, int neb, int nbuck,
                                              int* __restrict__ boff,
                                              int* __restrict__ rowptr, int N_) {
  __shared__ int s[256];
  int t = threadIdx.x;
  int sum = 0;
  if (t < nbuck) {
    #pragma unroll 8
    for (int r = 0; r < neb; ++r) sum += mat[r * nbuck + t];
  }
  s[t] = sum;
  __syncthreads();
  #pragma unroll
  for (int d = 1; d < 256; d <<= 1) {
    int u = (t >= d) ? s[t - d] : 0;
    __syncthreads();
    s[t] += u;
    __syncthreads();
  }
  if (t < nbuck) boff[t] = s[t] - sum;
  if (t == 0) { boff[nbuck] = s[255]; rowptr[N_] = s[255]; }
}

// one block per bucket: exclusive scan down OWN column of mat (in place; no cross-block
// sharing -> race-free) + zero pooling buffers
__global__ __launch_bounds__(256) void k_colscan(int* __restrict__ mat, int neb, int nbuck,
                                                 const int* __restrict__ boff,
                                                 float* __restrict__ sums,
                                                 int* __restrict__ cnt, int ng) {
  __shared__ int s[256];
  int b = blockIdx.x, t = threadIdx.x;
  int v = (t < neb) ? mat[t * nbuck + b] : 0;
  s[t] = v;
  __syncthreads();
  #pragma unroll
  for (int d = 1; d < 256; d <<= 1) {
    int u = (t >= d) ? s[t - d] : 0;
    __syncthreads();
    s[t] += u;
    __syncthreads();
  }
  if (t < neb) mat[t * nbuck + b] = boff[b] + s[t] - v;
  int tot_e = ng * 128;
  for (int i = b * 256 + t; i < tot_e; i += gridDim.x * 256) sums[i] = 0.f;
  for (int i = b * 256 + t; i < ng; i += gridDim.x * 256) cnt[i] = 0;
}

// scatter edges into bucket-grouped staging: staged = (dst&255)<<16 | src  (uint16 each)
__global__ __launch_bounds__(256) void k_part(const int* __restrict__ src,
                                              const int* __restrict__ dst, int E, int nbuck,
                                              const int* __restrict__ mat,
                                              unsigned* __restrict__ staged) {
  __shared__ int cur[256];
  int t = threadIdx.x;
  if (t < nbuck) cur[t] = mat[blockIdx.x * nbuck + t];
  __syncthreads();
  int e0 = blockIdx.x * EPB, e1 = min(e0 + EPB, E);
  for (int e = e0 + t; e < e1; e += 256) {
    int d = dst[e];
    int pos = atomicAdd(&cur[d >> 8], 1);
    staged[pos] = ((unsigned)(d & 255) << 16) | (unsigned)src[e];
  }
}

// one block per bucket: per-node count (LDS) -> rowptr + dinv, then place csr entries (uint16)
__global__ __launch_bounds__(256) void k_csr(const unsigned* __restrict__ staged,
                                             const int* __restrict__ boff, int N_,
                                             float* __restrict__ dinv, int* __restrict__ rowptr,
                                             unsigned short* __restrict__ csr16) {
  __shared__ int cnt[256];
  __shared__ int cur[256];
  int b = blockIdx.x, t = threadIdx.x;
  int lo = boff[b], hi = boff[b + 1];
  cnt[t] = 0;
  __syncthreads();
  for (int i = lo + t; i < hi; i += 256) atomicAdd(&cnt[staged[i] >> 16], 1);
  __syncthreads();
  int v = cnt[t];
  #pragma unroll
  for (int d = 1; d < 256; d <<= 1) {
    int u = (t >= d) ? cnt[t - d] : 0;
    __syncthreads();
    cnt[t] += u;
    __syncthreads();
  }
  int start = lo + cnt[t] - v;     // exclusive within bucket
  cur[t] = start;
  int node = (b << 8) + t;
  if (node < N_) {
    rowptr[node] = start;
    dinv[node] = rsqrtf((float)(v + 1));
  }
  __syncthreads();
  for (int i = lo + t; i < hi; i += 256) {
    unsigned e = staged[i];
    int pos = atomicAdd(&cur[e >> 16], 1);
    csr16[pos] = (unsigned short)(e & 0xFFFFu);
  }
}

// Out[r][c] = bf16( (sum_k A[r][k]*W[k][c]) * dinv[r] ).  A: f32 (A_F32=1) or bf16.
template<int A_F32>
__global__ __launch_bounds__(256) void k_mfma_gemm(
    const void* __restrict__ Ap, const unsigned short* __restrict__ Wt,
    const float* __restrict__ dinv, unsigned short* __restrict__ Out, int M)
{
  int wv = threadIdx.x >> 6, lane = threadIdx.x & 63;
  int r0 = blockIdx.x * 64 + wv * 16;
  if (r0 >= M) return;
  int arow = r0 + (lane & 15);
  int kb = (lane >> 4) * 8;
  short8 a[4];
  if (A_F32) {
    const float* Ar = (const float*)Ap + (size_t)arow * 128 + kb;
    #pragma unroll
    for (int ks = 0; ks < 4; ++ks) {
      float4 u = *(const float4*)(Ar + ks * 32);
      float4 v = *(const float4*)(Ar + ks * 32 + 4);
      short8 tt;
      tt[0] = (short)f2b(u.x); tt[1] = (short)f2b(u.y);
      tt[2] = (short)f2b(u.z); tt[3] = (short)f2b(u.w);
      tt[4] = (short)f2b(v.x); tt[5] = (short)f2b(v.y);
      tt[6] = (short)f2b(v.z); tt[7] = (short)f2b(v.w);
      a[ks] = tt;
    }
  } else {
    const unsigned short* Ar = (const unsigned short*)Ap + (size_t)arow * 128 + kb;
    #pragma unroll
    for (int ks = 0; ks < 4; ++ks)
      a[ks] = *(const short8*)(Ar + ks * 32);
  }
  f32x4 acc[8];
  #pragma unroll
  for (int i = 0; i < 8; ++i) acc[i] = (f32x4){0.f, 0.f, 0.f, 0.f};
  const unsigned short* Bc = Wt + (size_t)(lane & 15) * 128 + kb;
  #pragma unroll
  for (int ct = 0; ct < 8; ++ct) {
    const unsigned short* B = Bc + ct * 16 * 128;
    #pragma unroll
    for (int ks = 0; ks < 4; ++ks)
      acc[ct] = __builtin_amdgcn_mfma_f32_16x16x32_bf16(
          a[ks], *(const short8*)(B + ks * 32), acc[ct], 0, 0, 0);
  }
  int orow = r0 + (lane >> 4) * 4;
  int ocol = lane & 15;
  float s0 = dinv[orow], s1 = dinv[orow + 1], s2 = dinv[orow + 2], s3 = dinv[orow + 3];
  #pragma unroll
  for (int ct = 0; ct < 8; ++ct) {
    unsigned short* o = Out + (size_t)orow * 128 + ct * 16 + ocol;
    o[0]   = f2b(acc[ct][0] * s0);
    o[128] = f2b(acc[ct][1] * s1);
    o[256] = f2b(acc[ct][2] * s2);
    o[384] = f2b(acc[ct][3] * s3);
  }
}

// half-wave (32 lanes) per dst node, uint2 (4 cols) per lane, 4-wide unrolled edge loop
__global__ __launch_bounds__(256) void k_gather_post(
    const unsigned short* __restrict__ csr16, const int* __restrict__ rowptr,
    const unsigned short* __restrict__ P, const float* __restrict__ dinv,
    const float* __restrict__ bias, unsigned short* __restrict__ R, int n)
{
  int node = blockIdx.x * 8 + (threadIdx.x >> 5);
  if (node >= n) return;
  int lane = threadIdx.x & 31;
  int lo = rowptr[node], hi = rowptr[node + 1];
  float a0 = 0.f, a1 = 0.f, a2 = 0.f, a3 = 0.f;
  int e = lo;
  for (; e + 4 <= hi; e += 4) {
    int s0 = csr16[e], s1 = csr16[e + 1], s2 = csr16[e + 2], s3 = csr16[e + 3];
    uint2 v0 = ((const uint2*)(P + (size_t)s0 * 128))[lane];
    uint2 v1 = ((const uint2*)(P + (size_t)s1 * 128))[lane];
    uint2 v2 = ((const uint2*)(P + (size_t)s2 * 128))[lane];
    uint2 v3 = ((const uint2*)(P + (size_t)s3 * 128))[lane];
    a0 += b2f_lo(v0.x) + b2f_lo(v1.x) + b2f_lo(v2.x) + b2f_lo(v3.x);
    a1 += b2f_hi(v0.x) + b2f_hi(v1.x) + b2f_hi(v2.x) + b2f_hi(v3.x);
    a2 += b2f_lo(v0.y) + b2f_lo(v1.y) + b2f_lo(v2.y) + b2f_lo(v3.y);
    a3 += b2f_hi(v0.y) + b2f_hi(v1.y) + b2f_hi(v2.y) + b2f_hi(v3.y);
  }
  for (; e < hi; ++e) {
    int s = csr16[e];
    uint2 v = ((const uint2*)(P + (size_t)s * 128))[lane];
    a0 += b2f_lo(v.x); a1 += b2f_hi(v.x);
    a2 += b2f_lo(v.y); a3 += b2f_hi(v.y);
  }
  float dv = dinv[node];
  uint2 hv = ((const uint2*)(P + (size_t)node * 128))[lane];
  float4 bb = ((const float4*)bias)[lane];
  float r0 = fmaxf(dv * (a0 + b2f_lo(hv.x)) + bb.x, 0.f);
  float r1 = fmaxf(dv * (a1 + b2f_hi(hv.x)) + bb.y, 0.f);
  float r2 = fmaxf(dv * (a2 + b2f_lo(hv.y)) + bb.z, 0.f);
  float r3 = fmaxf(dv * (a3 + b2f_hi(hv.y)) + bb.w, 0.f);
  uint2 pack;
  pack.x = (unsigned)f2b(r0) | ((unsigned)f2b(r1) << 16);
  pack.y = (unsigned)f2b(r2) | ((unsigned)f2b(r3) << 16);
  ((uint2*)(R + (size_t)node * 128))[lane] = pack;
}

// segmented mean-pool partial sums (batch sorted): wave owns RPW contiguous rows
__global__ __launch_bounds__(256) void k_pool_sum(
    const unsigned short* __restrict__ h2, const int* __restrict__ batch, int n,
    float* __restrict__ sums, int* __restrict__ cnt)
{
  int wid = blockIdx.x * 4 + (threadIdx.x >> 6);
  int lane = threadIdx.x & 63;
  int r0 = wid * RPW;
  if (r0 >= n) return;
  int r1 = min(r0 + RPW, n);
  const unsigned* H = (const unsigned*)h2;
  int gcur = batch[r0];
  float ax = 0.f, ay = 0.f;
  int run = 0;
  for (int r = r0; r < r1; ++r) {
    int g = batch[r];
    if (g != gcur) {
      atomicAdd(&sums[(size_t)gcur * 128 + 2 * lane], ax);
      atomicAdd(&sums[(size_t)gcur * 128 + 2 * lane + 1], ay);
      if (lane == 0) atomicAdd(&cnt[gcur], run);
      ax = ay = 0.f; run = 0; gcur = g;
    }
    unsigned v = H[(size_t)r * 64 + lane];
    ax += b2f_lo(v); ay += b2f_hi(v); ++run;
  }
  atomicAdd(&sums[(size_t)gcur * 128 + 2 * lane], ax);
  atomicAdd(&sums[(size_t)gcur * 128 + 2 * lane + 1], ay);
  if (lane == 0) atomicAdd(&cnt[gcur], run);
}

// per-graph MLP head: 4-chain ILP FC1, LDS-tree FC2
__global__ __launch_bounds__(128) void k_fc(
    const float* __restrict__ sums, const int* __restrict__ cnt,
    const float* __restrict__ Wf1, const float* __restrict__ bf1,
    const float* __restrict__ Wf2, const float* __restrict__ bf2,
    float* __restrict__ out)
{
  __shared__ float gl[128];
  __shared__ float red0[128];
  __shared__ float red1[128];
  int g = blockIdx.x, t = threadIdx.x;
  float c = (float)cnt[g];
  gl[t] = sums[(size_t)g * 128 + t] / fmaxf(c, 1.f);
  __syncthreads();
  float z0 = 0.f, z1 = 0.f, z2 = 0.f, z3 = 0.f;
  #pragma unroll
  for (int k = 0; k < 32; ++k) {
    z0 += gl[k]      * Wf1[k * 128 + t];
    z1 += gl[k + 32] * Wf1[(k + 32) * 128 + t];
    z2 += gl[k + 64] * Wf1[(k + 64) * 128 + t];
    z3 += gl[k + 96] * Wf1[(k + 96) * 128 + t];
  }
  float z = fmaxf((z0 + z1) + (z2 + z3) + bf1[t], 0.f);
  red0[t] = z * Wf2[2 * t];
  red1[t] = z * Wf2[2 * t + 1];
  __syncthreads();
  #pragma unroll
  for (int d = 64; d > 0; d >>= 1) {
    if (t < d) { red0[t] += red0[t + d]; red1[t] += red1[t + d]; }
    __syncthreads();
  }
  if (t == 0) {
    out[g * 2]     = red0[0] + bf2[0];
    out[g * 2 + 1] = red1[0] + bf2[1];
  }
}

extern "C" void kernel_launch(void* const* d_in, const int* in_sizes, int n_in,
                              void* d_out, int out_size, void* d_ws, size_t ws_size,
                              hipStream_t stream) {
  const float* x    = (const float*)d_in[0];
  const int*   ei   = (const int*)d_in[1];
  const int*   batch= (const int*)d_in[2];
  const float* W1   = (const float*)d_in[3];
  const float* b1   = (const float*)d_in[4];
  const float* W2   = (const float*)d_in[5];
  const float* b2   = (const float*)d_in[6];
  const float* Wf1  = (const float*)d_in[7];
  const float* bf1  = (const float*)d_in[8];
  const float* Wf2  = (const float*)d_in[9];
  const float* bf2  = (const float*)d_in[10];
  float* out = (float*)d_out;

  const int N  = in_sizes[0] / 128;    // requires N < 65536 for uint16 csr entries
  const int E  = in_sizes[1] / 2;
  const int NG = out_size / 2;
  const int* srcp = ei;
  const int* dstp = ei + E;

  const int nbuck = (N + BKT - 1) / BKT;     // <= 256
  const int neb   = (E + EPB - 1) / EPB;     // <= 256

  char* ws = (char*)d_ws;
  size_t off = 0;
  auto carve = [&](size_t bytes) { void* p = ws + off; off += (bytes + 255) & ~(size_t)255; return p; };
  float* dinv   = (float*)carve((size_t)N * 4);
  int*   rowptr = (int*)  carve((size_t)(N + 1) * 4);
  int*   boff   = (int*)  carve((size_t)(nbuck + 1) * 4);
  int*   mat    = (int*)  carve((size_t)neb * nbuck * 4);
  unsigned*       staged = (unsigned*)      carve((size_t)E * 4);
  unsigned short* csr16  = (unsigned short*)carve((size_t)E * 2);
  unsigned short* Wt1 = (unsigned short*)carve(128 * 128 * 2);
  unsigned short* Wt2 = (unsigned short*)carve(128 * 128 * 2);
  float* sums   = (float*)carve((size_t)NG * 128 * 4);
  int*   cntg   = (int*)  carve((size_t)NG * 4);
  const size_t nb_row = (size_t)N * 128 * 2;   // bf16 rows
  unsigned short* U0 = (unsigned short*)carve(nb_row);
  unsigned short* U1 = (unsigned short*)carve(nb_row);

  // fused weight-prep + histogram
  k_setup<<<32 + neb, 256, 0, stream>>>(W1, Wt1, W2, Wt2, dstp, E, nbuck, mat);
  // bucket totals + offsets (1 block), then per-column bases (in place) + zero pooling bufs
  k_excl   <<<1, 256, 0, stream>>>(mat, neb, nbuck, boff, rowptr, N);
  k_colscan<<<nbuck, 256, 0, stream>>>(mat, neb, nbuck, boff, sums, cntg, NG);
  k_part<<<neb, 256, 0, stream>>>(srcp, dstp, E, nbuck, mat, staged);
  k_csr <<<nbuck, 256, 0, stream>>>(staged, boff, N, dinv, rowptr, csr16);

  const int gblocks = (N + 63) / 64;
  // layer 1
  k_mfma_gemm<1><<<gblocks, 256, 0, stream>>>(x, Wt1, dinv, U0, N);
  k_gather_post<<<(N + 7) / 8, 256, 0, stream>>>(csr16, rowptr, U0, dinv, b1, U1, N);
  // layer 2
  k_mfma_gemm<0><<<gblocks, 256, 0, stream>>>(U1, Wt2, dinv, U0, N);
  k_gather_post<<<(N + 7) / 8, 256, 0, stream>>>(csr16, rowptr, U0, dinv, b2, U1, N);

  // pooling + MLP head
  const int pblocks = (N + RPW * 4 - 1) / (RPW * 4);
  k_pool_sum<<<pblocks, 256, 0, stream>>>(U1, batch, N, sums, cntg);
  k_fc<<<NG, 128, 0, stream>>>(sums, cntg, Wf1, bf1, Wf2, bf2, out);
}

// Round 11
// 160.892 us; speedup vs baseline: 1.3242x; 1.1022x over previous
//
#include <hip/hip_runtime.h>

typedef __attribute__((ext_vector_type(8))) short short8;
typedef __attribute__((ext_vector_type(4))) float f32x4;

__device__ __forceinline__ unsigned short f2b(float x) {
  unsigned u = __float_as_uint(x);
  u += 0x7FFF + ((u >> 16) & 1);           // round-to-nearest-even
  return (unsigned short)(u >> 16);
}
__device__ __forceinline__ float b2f_lo(unsigned v) { return __uint_as_float(v << 16); }
__device__ __forceinline__ float b2f_hi(unsigned v) { return __uint_as_float(v & 0xFFFF0000u); }

#define EPB 4096   // edges per partition block
#define BKT 256    // nodes per bucket
#define RPW 32     // rows per wave in pooling

// fused setup: blocks [0,16) prepW W1, [16,32) prepW W2, [32, 32+neb) histogram
__global__ __launch_bounds__(256) void k_setup(
    const float* __restrict__ W1, unsigned short* __restrict__ Wt1,
    const float* __restrict__ W2, unsigned short* __restrict__ Wt2,
    const int* __restrict__ dst, int E, int nbuck, int* __restrict__ mat)
{
  __shared__ float tile[32][33];
  __shared__ int h[256];
  int t = threadIdx.x;
  if (blockIdx.x < 32) {
    const float* W = (blockIdx.x < 16) ? W1 : W2;
    unsigned short* Wt = (blockIdx.x < 16) ? Wt1 : Wt2;
    int bid = blockIdx.x & 15;
    int tx = t & 31, ty = t >> 5;
    int bx = bid & 3, by = bid >> 2;
    #pragma unroll
    for (int i = 0; i < 4; ++i)
      tile[ty + i * 8][tx] = W[(by * 32 + ty + i * 8) * 128 + bx * 32 + tx];
    __syncthreads();
    #pragma unroll
    for (int i = 0; i < 4; ++i)
      Wt[(bx * 32 + ty + i * 8) * 128 + by * 32 + tx] = f2b(tile[tx][ty + i * 8]);
  } else {
    int blk = blockIdx.x - 32;
    h[t] = 0;
    __syncthreads();
    int e0 = blk * EPB, e1 = min(e0 + EPB, E);
    for (int e = e0 + t; e < e1; e += 256) atomicAdd(&h[dst[e] >> 8], 1);
    __syncthreads();
    if (t < nbuck) mat[blk * nbuck + t] = h[t];
  }
}

// ONE block: bucket totals = column sums of mat (coalesced, unrolled), scan -> boff,
// init global cursors = boff
__global__ __launch_bounds__(256) void k_excl(const int* __restrict__ mat, int neb, int nbuck,
                                              int* __restrict__ boff, int* __restrict__ cursor,
                                              int* __restrict__ rowptr, int N_) {
  __shared__ int s[256];
  int t = threadIdx.x;
  int sum = 0;
  if (t < nbuck) {
    #pragma unroll 8
    for (int r = 0; r < neb; ++r) sum += mat[r * nbuck + t];
  }
  s[t] = sum;
  __syncthreads();
  #pragma unroll
  for (int d = 1; d < 256; d <<= 1) {
    int u = (t >= d) ? s[t - d] : 0;
    __syncthreads();
    s[t] += u;
    __syncthreads();
  }
  if (t < nbuck) { boff[t] = s[t] - sum; cursor[t] = s[t] - sum; }
  if (t == 0) { boff[nbuck] = s[255]; rowptr[N_] = s[255]; }
}

// scatter edges into bucket-grouped staging via dynamic range claiming:
// block claims atomicAdd(cursor[bucket], own_count) -> contiguous base.
// Also zeroes the pooling buffers (sums, cnt).
__global__ __launch_bounds__(256) void k_part(const int* __restrict__ src,
                                              const int* __restrict__ dst, int E, int nbuck,
                                              const int* __restrict__ mat,
                                              int* __restrict__ cursor,
                                              unsigned* __restrict__ staged,
                                              float* __restrict__ sums,
                                              int* __restrict__ cnt, int ng) {
  __shared__ int cur[256];
  int t = threadIdx.x;
  if (t < nbuck) {
    int c = mat[blockIdx.x * nbuck + t];
    cur[t] = c ? atomicAdd(&cursor[t], c) : 0;
  }
  __syncthreads();
  int e0 = blockIdx.x * EPB, e1 = min(e0 + EPB, E);
  for (int e = e0 + t; e < e1; e += 256) {
    int d = dst[e];
    int pos = atomicAdd(&cur[d >> 8], 1);
    staged[pos] = ((unsigned)(d & 255) << 16) | (unsigned)src[e];
  }
  // zero pooling buffers (grid-stride)
  int tot_e = ng * 128;
  for (int i = blockIdx.x * 256 + t; i < tot_e; i += gridDim.x * 256) sums[i] = 0.f;
  for (int i = blockIdx.x * 256 + t; i < ng; i += gridDim.x * 256) cnt[i] = 0;
}

// one block per bucket: per-node count (LDS) -> rowptr + dinv, then place csr entries (uint16)
__global__ __launch_bounds__(256) void k_csr(const unsigned* __restrict__ staged,
                                             const int* __restrict__ boff, int N_,
                                             float* __restrict__ dinv, int* __restrict__ rowptr,
                                             unsigned short* __restrict__ csr16) {
  __shared__ int cnt[256];
  __shared__ int cur[256];
  int b = blockIdx.x, t = threadIdx.x;
  int lo = boff[b], hi = boff[b + 1];
  cnt[t] = 0;
  __syncthreads();
  for (int i = lo + t; i < hi; i += 256) atomicAdd(&cnt[staged[i] >> 16], 1);
  __syncthreads();
  int v = cnt[t];
  #pragma unroll
  for (int d = 1; d < 256; d <<= 1) {
    int u = (t >= d) ? cnt[t - d] : 0;
    __syncthreads();
    cnt[t] += u;
    __syncthreads();
  }
  int start = lo + cnt[t] - v;     // exclusive within bucket
  cur[t] = start;
  int node = (b << 8) + t;
  if (node < N_) {
    rowptr[node] = start;
    dinv[node] = rsqrtf((float)(v + 1));
  }
  __syncthreads();
  for (int i = lo + t; i < hi; i += 256) {
    unsigned e = staged[i];
    int pos = atomicAdd(&cur[e >> 16], 1);
    csr16[pos] = (unsigned short)(e & 0xFFFFu);
  }
}

// Out[r][c] = bf16( (sum_k A[r][k]*W[k][c]) * dinv[r] ).  A: f32 (A_F32=1) or bf16.
// B-frags register-resident (loaded once per wave); each wave does 2 row-tiles (32 rows).
template<int A_F32>
__global__ __launch_bounds__(256) void k_mfma_gemm(
    const void* __restrict__ Ap, const unsigned short* __restrict__ Wt,
    const float* __restrict__ dinv, unsigned short* __restrict__ Out, int M)
{
  int wv = threadIdx.x >> 6, lane = threadIdx.x & 63;
  int kb = (lane >> 4) * 8;
  // load all B-frags once: 8 col-tiles x 4 k-slices (128 VGPRs)
  short8 bf[8][4];
  const unsigned short* Bc = Wt + (size_t)(lane & 15) * 128 + kb;
  #pragma unroll
  for (int ct = 0; ct < 8; ++ct)
    #pragma unroll
    for (int ks = 0; ks < 4; ++ks)
      bf[ct][ks] = *(const short8*)(Bc + ct * 16 * 128 + ks * 32);

  int r0 = (blockIdx.x * 4 + wv) * 32;
  #pragma unroll
  for (int rt = 0; rt < 2; ++rt) {
    int rbase = r0 + rt * 16;
    if (rbase >= M) return;            // wave-uniform
    int arow = rbase + (lane & 15);
    short8 a[4];
    if (A_F32) {
      const float* Ar = (const float*)Ap + (size_t)arow * 128 + kb;
      #pragma unroll
      for (int ks = 0; ks < 4; ++ks) {
        float4 u = *(const float4*)(Ar + ks * 32);
        float4 v = *(const float4*)(Ar + ks * 32 + 4);
        short8 tt;
        tt[0] = (short)f2b(u.x); tt[1] = (short)f2b(u.y);
        tt[2] = (short)f2b(u.z); tt[3] = (short)f2b(u.w);
        tt[4] = (short)f2b(v.x); tt[5] = (short)f2b(v.y);
        tt[6] = (short)f2b(v.z); tt[7] = (short)f2b(v.w);
        a[ks] = tt;
      }
    } else {
      const unsigned short* Ar = (const unsigned short*)Ap + (size_t)arow * 128 + kb;
      #pragma unroll
      for (int ks = 0; ks < 4; ++ks)
        a[ks] = *(const short8*)(Ar + ks * 32);
    }
    f32x4 acc[8];
    #pragma unroll
    for (int i = 0; i < 8; ++i) acc[i] = (f32x4){0.f, 0.f, 0.f, 0.f};
    #pragma unroll
    for (int ct = 0; ct < 8; ++ct)
      #pragma unroll
      for (int ks = 0; ks < 4; ++ks)
        acc[ct] = __builtin_amdgcn_mfma_f32_16x16x32_bf16(a[ks], bf[ct][ks], acc[ct], 0, 0, 0);
    int orow = rbase + (lane >> 4) * 4;
    int ocol = lane & 15;
    float s0 = dinv[orow], s1 = dinv[orow + 1], s2 = dinv[orow + 2], s3 = dinv[orow + 3];
    #pragma unroll
    for (int ct = 0; ct < 8; ++ct) {
      unsigned short* o = Out + (size_t)orow * 128 + ct * 16 + ocol;
      o[0]   = f2b(acc[ct][0] * s0);
      o[128] = f2b(acc[ct][1] * s1);
      o[256] = f2b(acc[ct][2] * s2);
      o[384] = f2b(acc[ct][3] * s3);
    }
  }
}

// half-wave (32 lanes) per dst node, uint2 (4 cols) per lane, 8-wide unrolled edge loop
__global__ __launch_bounds__(256) void k_gather_post(
    const unsigned short* __restrict__ csr16, const int* __restrict__ rowptr,
    const unsigned short* __restrict__ P, const float* __restrict__ dinv,
    const float* __restrict__ bias, unsigned short* __restrict__ R, int n)
{
  int node = blockIdx.x * 8 + (threadIdx.x >> 5);
  if (node >= n) return;
  int lane = threadIdx.x & 31;
  int lo = rowptr[node], hi = rowptr[node + 1];
  float a0 = 0.f, a1 = 0.f, a2 = 0.f, a3 = 0.f;
  int e = lo;
  for (; e + 8 <= hi; e += 8) {
    int s0 = csr16[e],     s1 = csr16[e + 1], s2 = csr16[e + 2], s3 = csr16[e + 3];
    int s4 = csr16[e + 4], s5 = csr16[e + 5], s6 = csr16[e + 6], s7 = csr16[e + 7];
    uint2 v0 = ((const uint2*)(P + (size_t)s0 * 128))[lane];
    uint2 v1 = ((const uint2*)(P + (size_t)s1 * 128))[lane];
    uint2 v2 = ((const uint2*)(P + (size_t)s2 * 128))[lane];
    uint2 v3 = ((const uint2*)(P + (size_t)s3 * 128))[lane];
    uint2 v4 = ((const uint2*)(P + (size_t)s4 * 128))[lane];
    uint2 v5 = ((const uint2*)(P + (size_t)s5 * 128))[lane];
    uint2 v6 = ((const uint2*)(P + (size_t)s6 * 128))[lane];
    uint2 v7 = ((const uint2*)(P + (size_t)s7 * 128))[lane];
    a0 += b2f_lo(v0.x) + b2f_lo(v1.x) + b2f_lo(v2.x) + b2f_lo(v3.x)
        + b2f_lo(v4.x) + b2f_lo(v5.x) + b2f_lo(v6.x) + b2f_lo(v7.x);
    a1 += b2f_hi(v0.x) + b2f_hi(v1.x) + b2f_hi(v2.x) + b2f_hi(v3.x)
        + b2f_hi(v4.x) + b2f_hi(v5.x) + b2f_hi(v6.x) + b2f_hi(v7.x);
    a2 += b2f_lo(v0.y) + b2f_lo(v1.y) + b2f_lo(v2.y) + b2f_lo(v3.y)
        + b2f_lo(v4.y) + b2f_lo(v5.y) + b2f_lo(v6.y) + b2f_lo(v7.y);
    a3 += b2f_hi(v0.y) + b2f_hi(v1.y) + b2f_hi(v2.y) + b2f_hi(v3.y)
        + b2f_hi(v4.y) + b2f_hi(v5.y) + b2f_hi(v6.y) + b2f_hi(v7.y);
  }
  for (; e + 4 <= hi; e += 4) {
    int s0 = csr16[e], s1 = csr16[e + 1], s2 = csr16[e + 2], s3 = csr16[e + 3];
    uint2 v0 = ((const uint2*)(P + (size_t)s0 * 128))[lane];
    uint2 v1 = ((const uint2*)(P + (size_t)s1 * 128))[lane];
    uint2 v2 = ((const uint2*)(P + (size_t)s2 * 128))[lane];
    uint2 v3 = ((const uint2*)(P + (size_t)s3 * 128))[lane];
    a0 += b2f_lo(v0.x) + b2f_lo(v1.x) + b2f_lo(v2.x) + b2f_lo(v3.x);
    a1 += b2f_hi(v0.x) + b2f_hi(v1.x) + b2f_hi(v2.x) + b2f_hi(v3.x);
    a2 += b2f_lo(v0.y) + b2f_lo(v1.y) + b2f_lo(v2.y) + b2f_lo(v3.y);
    a3 += b2f_hi(v0.y) + b2f_hi(v1.y) + b2f_hi(v2.y) + b2f_hi(v3.y);
  }
  for (; e < hi; ++e) {
    int s = csr16[e];
    uint2 v = ((const uint2*)(P + (size_t)s * 128))[lane];
    a0 += b2f_lo(v.x); a1 += b2f_hi(v.x);
    a2 += b2f_lo(v.y); a3 += b2f_hi(v.y);
  }
  float dv = dinv[node];
  uint2 hv = ((const uint2*)(P + (size_t)node * 128))[lane];
  float4 bb = ((const float4*)bias)[lane];
  float r0 = fmaxf(dv * (a0 + b2f_lo(hv.x)) + bb.x, 0.f);
  float r1 = fmaxf(dv * (a1 + b2f_hi(hv.x)) + bb.y, 0.f);
  float r2 = fmaxf(dv * (a2 + b2f_lo(hv.y)) + bb.z, 0.f);
  float r3 = fmaxf(dv * (a3 + b2f_hi(hv.y)) + bb.w, 0.f);
  uint2 pack;
  pack.x = (unsigned)f2b(r0) | ((unsigned)f2b(r1) << 16);
  pack.y = (unsigned)f2b(r2) | ((unsigned)f2b(r3) << 16);
  ((uint2*)(R + (size_t)node * 128))[lane] = pack;
}

// segmented mean-pool partial sums (batch sorted): wave owns RPW contiguous rows
__global__ __launch_bounds__(256) void k_pool_sum(
    const unsigned short* __restrict__ h2, const int* __restrict__ batch, int n,
    float* __restrict__ sums, int* __restrict__ cnt)
{
  int wid = blockIdx.x * 4 + (threadIdx.x >> 6);
  int lane = threadIdx.x & 63;
  int r0 = wid * RPW;
  if (r0 >= n) return;
  int r1 = min(r0 + RPW, n);
  const unsigned* H = (const unsigned*)h2;
  int gcur = batch[r0];
  float ax = 0.f, ay = 0.f;
  int run = 0;
  for (int r = r0; r < r1; ++r) {
    int g = batch[r];
    if (g != gcur) {
      atomicAdd(&sums[(size_t)gcur * 128 + 2 * lane], ax);
      atomicAdd(&sums[(size_t)gcur * 128 + 2 * lane + 1], ay);
      if (lane == 0) atomicAdd(&cnt[gcur], run);
      ax = ay = 0.f; run = 0; gcur = g;
    }
    unsigned v = H[(size_t)r * 64 + lane];
    ax += b2f_lo(v); ay += b2f_hi(v); ++run;
  }
  atomicAdd(&sums[(size_t)gcur * 128 + 2 * lane], ax);
  atomicAdd(&sums[(size_t)gcur * 128 + 2 * lane + 1], ay);
  if (lane == 0) atomicAdd(&cnt[gcur], run);
}

// per-graph MLP head: 4-chain ILP FC1, LDS-tree FC2
__global__ __launch_bounds__(128) void k_fc(
    const float* __restrict__ sums, const int* __restrict__ cnt,
    const float* __restrict__ Wf1, const float* __restrict__ bf1,
    const float* __restrict__ Wf2, const float* __restrict__ bf2,
    float* __restrict__ out)
{
  __shared__ float gl[128];
  __shared__ float red0[128];
  __shared__ float red1[128];
  int g = blockIdx.x, t = threadIdx.x;
  float c = (float)cnt[g];
  gl[t] = sums[(size_t)g * 128 + t] / fmaxf(c, 1.f);
  __syncthreads();
  float z0 = 0.f, z1 = 0.f, z2 = 0.f, z3 = 0.f;
  #pragma unroll
  for (int k = 0; k < 32; ++k) {
    z0 += gl[k]      * Wf1[k * 128 + t];
    z1 += gl[k + 32] * Wf1[(k + 32) * 128 + t];
    z2 += gl[k + 64] * Wf1[(k + 64) * 128 + t];
    z3 += gl[k + 96] * Wf1[(k + 96) * 128 + t];
  }
  float z = fmaxf((z0 + z1) + (z2 + z3) + bf1[t], 0.f);
  red0[t] = z * Wf2[2 * t];
  red1[t] = z * Wf2[2 * t + 1];
  __syncthreads();
  #pragma unroll
  for (int d = 64; d > 0; d >>= 1) {
    if (t < d) { red0[t] += red0[t + d]; red1[t] += red1[t + d]; }
    __syncthreads();
  }
  if (t == 0) {
    out[g * 2]     = red0[0] + bf2[0];
    out[g * 2 + 1] = red1[0] + bf2[1];
  }
}

extern "C" void kernel_launch(void* const* d_in, const int* in_sizes, int n_in,
                              void* d_out, int out_size, void* d_ws, size_t ws_size,
                              hipStream_t stream) {
  const float* x    = (const float*)d_in[0];
  const int*   ei   = (const int*)d_in[1];
  const int*   batch= (const int*)d_in[2];
  const float* W1   = (const float*)d_in[3];
  const float* b1   = (const float*)d_in[4];
  const float* W2   = (const float*)d_in[5];
  const float* b2   = (const float*)d_in[6];
  const float* Wf1  = (const float*)d_in[7];
  const float* bf1  = (const float*)d_in[8];
  const float* Wf2  = (const float*)d_in[9];
  const float* bf2  = (const float*)d_in[10];
  float* out = (float*)d_out;

  const int N  = in_sizes[0] / 128;    // requires N < 65536 for uint16 csr entries
  const int E  = in_sizes[1] / 2;
  const int NG = out_size / 2;
  const int* srcp = ei;
  const int* dstp = ei + E;

  const int nbuck = (N + BKT - 1) / BKT;     // <= 256
  const int neb   = (E + EPB - 1) / EPB;     // <= 256

  char* ws = (char*)d_ws;
  size_t off = 0;
  auto carve = [&](size_t bytes) { void* p = ws + off; off += (bytes + 255) & ~(size_t)255; return p; };
  float* dinv   = (float*)carve((size_t)N * 4);
  int*   rowptr = (int*)  carve((size_t)(N + 1) * 4);
  int*   boff   = (int*)  carve((size_t)(nbuck + 1) * 4);
  int*   cursor = (int*)  carve((size_t)256 * 4);
  int*   mat    = (int*)  carve((size_t)neb * nbuck * 4);
  unsigned*       staged = (unsigned*)      carve((size_t)E * 4);
  unsigned short* csr16  = (unsigned short*)carve((size_t)E * 2);
  unsigned short* Wt1 = (unsigned short*)carve(128 * 128 * 2);
  unsigned short* Wt2 = (unsigned short*)carve(128 * 128 * 2);
  float* sums   = (float*)carve((size_t)NG * 128 * 4);
  int*   cntg   = (int*)  carve((size_t)NG * 4);
  const size_t nb_row = (size_t)N * 128 * 2;   // bf16 rows
  unsigned short* U0 = (unsigned short*)carve(nb_row);
  unsigned short* U1 = (unsigned short*)carve(nb_row);

  // fused weight-prep + histogram
  k_setup<<<32 + neb, 256, 0, stream>>>(W1, Wt1, W2, Wt2, dstp, E, nbuck, mat);
  // bucket totals + offsets + cursor init (1 block)
  k_excl<<<1, 256, 0, stream>>>(mat, neb, nbuck, boff, cursor, rowptr, N);
  // partition with dynamic range claiming (+ zero pooling buffers)
  k_part<<<neb, 256, 0, stream>>>(srcp, dstp, E, nbuck, mat, cursor, staged, sums, cntg, NG);
  k_csr <<<nbuck, 256, 0, stream>>>(staged, boff, N, dinv, rowptr, csr16);

  const int gblocks = (N + 127) / 128;
  // layer 1
  k_mfma_gemm<1><<<gblocks, 256, 0, stream>>>(x, Wt1, dinv, U0, N);
  k_gather_post<<<(N + 7) / 8, 256, 0, stream>>>(csr16, rowptr, U0, dinv, b1, U1, N);
  // layer 2
  k_mfma_gemm<0><<<gblocks, 256, 0, stream>>>(U1, Wt2, dinv, U0, N);
  k_gather_post<<<(N + 7) / 8, 256, 0, stream>>>(csr16, rowptr, U0, dinv, b2, U1, N);

  // pooling + MLP head
  const int pblocks = (N + RPW * 4 - 1) / (RPW * 4);
  k_pool_sum<<<pblocks, 256, 0, stream>>>(U1, batch, N, sums, cntg);
  k_fc<<<NG, 128, 0, stream>>>(sums, cntg, Wf1, bf1, Wf2, bf2, out);
}